// Round 5
// baseline (409.011 us; speedup 1.0000x reference)
//
#include <hip/hip_runtime.h>

#define BATCH 32
#define SEQ   4096
#define HID   512
#define BLOCKS_PER_BATCH 64   // 4096 rows / (16 rows/wave * 4 waves)

typedef float f4 __attribute__((ext_vector_type(4)));

// v[b,h] = sum_o hidden[b,o] * W[o,h]   (b_attn cancels in softmax)
// grid (32, 2): block = (batch b, 256-wide h-half); o split across 4 waves,
// W read as float4. Also re-zeroes the per-batch arrival counters each call
// (graph replays reuse d_ws; kernel-boundary ordering makes zeros visible).
__global__ void __launch_bounds__(256) compute_v_kernel(
        const float* __restrict__ hidden,
        const float* __restrict__ W,
        float* __restrict__ v,
        int* __restrict__ counters) {
    int b    = blockIdx.x;
    int lane = threadIdx.x & 63;
    int wq   = threadIdx.x >> 6;               // o-quarter 0..3
    int h4   = blockIdx.y * 64 + lane;         // float4 column index 0..127

    if (blockIdx.y == 0 && threadIdx.x == 0) counters[b] = 0;

    __shared__ float sh[HID];
    for (int i = threadIdx.x; i < HID; i += 256) sh[i] = hidden[b * HID + i];
    __syncthreads();

    const f4* W4 = (const f4*)W;               // row o = 128 float4
    f4 acc = {0.f, 0.f, 0.f, 0.f};
    int o0 = wq * 128;
    #pragma unroll 8
    for (int o = o0; o < o0 + 128; ++o) {
        float s = sh[o];
        f4 w = W4[o * 128 + h4];
        acc.x = fmaf(s, w.x, acc.x);
        acc.y = fmaf(s, w.y, acc.y);
        acc.z = fmaf(s, w.z, acc.z);
        acc.w = fmaf(s, w.w, acc.w);
    }

    __shared__ f4 red[4][64];
    red[wq][lane] = acc;
    __syncthreads();
    if (wq == 0) {
        f4 r = red[0][lane];
        f4 a = red[1][lane], c = red[2][lane], d = red[3][lane];
        r.x += a.x + c.x + d.x;  r.y += a.y + c.y + d.y;
        r.z += a.z + c.z + d.z;  r.w += a.w + c.w + d.w;
        ((f4*)(v + (long long)b * HID))[h4] = r;
    }
}

// scores[b,s] = dot(enc[b,s,:], v[b,:]) for 64 rows/block, then the LAST
// block to finish within each batch runs that batch's softmax in-place.
// Device-scope fences are required: per-XCD L2s are not cross-coherent.
__global__ void __launch_bounds__(256) scores_softmax_kernel(
        const float* __restrict__ enc,
        const float* __restrict__ v,
        float* __restrict__ out,
        int* __restrict__ counters) {
    int wid  = blockIdx.x * 4 + (threadIdx.x >> 6);
    int lane = threadIdx.x & 63;
    int bb   = blockIdx.x >> 6;                 // batch (64 blocks per batch)
    long long row0 = (long long)wid * 16;

    const f4* v4 = (const f4*)(v + (long long)bb * HID);
    f4 v0 = v4[lane];                           // loaded once per wave
    f4 v1 = v4[lane + 64];

    for (int r = 0; r < 16; r += 4) {
        const f4* e0 = (const f4*)(enc + (row0 + r)     * HID);
        const f4* e1 = (const f4*)(enc + (row0 + r + 1) * HID);
        const f4* e2 = (const f4*)(enc + (row0 + r + 2) * HID);
        const f4* e3 = (const f4*)(enc + (row0 + r + 3) * HID);
        f4 a0 = e0[lane], a1 = e0[lane + 64];   // 8 coalesced float4 loads
        f4 b0 = e1[lane], b1 = e1[lane + 64];
        f4 c0 = e2[lane], c1 = e2[lane + 64];
        f4 d0 = e3[lane], d1 = e3[lane + 64];

        float accA = a0.x*v0.x + a0.y*v0.y + a0.z*v0.z + a0.w*v0.w
                   + a1.x*v1.x + a1.y*v1.y + a1.z*v1.z + a1.w*v1.w;
        float accB = b0.x*v0.x + b0.y*v0.y + b0.z*v0.z + b0.w*v0.w
                   + b1.x*v1.x + b1.y*v1.y + b1.z*v1.z + b1.w*v1.w;
        float accC = c0.x*v0.x + c0.y*v0.y + c0.z*v0.z + c0.w*v0.w
                   + c1.x*v1.x + c1.y*v1.y + c1.z*v1.z + c1.w*v1.w;
        float accD = d0.x*v0.x + d0.y*v0.y + d0.z*v0.z + d0.w*v0.w
                   + d1.x*v1.x + d1.y*v1.y + d1.z*v1.z + d1.w*v1.w;

        float zab = (lane < 32) ? accA : accB;
        zab += __shfl_xor((lane < 32) ? accB : accA, 32, 64);
        float zcd = (lane < 32) ? accC : accD;
        zcd += __shfl_xor((lane < 32) ? accD : accC, 32, 64);
        #pragma unroll
        for (int m = 16; m > 0; m >>= 1) {
            zab += __shfl_xor(zab, m, 64);
            zcd += __shfl_xor(zcd, m, 64);
        }
        if (lane == 0)  { out[row0 + r]     = zab; out[row0 + r + 2] = zcd; }
        if (lane == 32) { out[row0 + r + 1] = zab; out[row0 + r + 3] = zcd; }
    }

    // ---- arrival: release this block's score writes, bump batch counter ----
    __threadfence();                            // device-scope release
    __syncthreads();
    __shared__ int amLast;
    if (threadIdx.x == 0) {
        int prev = __hip_atomic_fetch_add(&counters[bb], 1,
                                          __ATOMIC_ACQ_REL,
                                          __HIP_MEMORY_SCOPE_AGENT);
        amLast = (prev == BLOCKS_PER_BATCH - 1);
    }
    __syncthreads();
    if (!amLast) return;
    __threadfence();                            // device-scope acquire

    // ---- softmax over out[bb*SEQ .. +4096], 256 threads x 16 values ----
    f4* row4 = (f4*)(out + (long long)bb * SEQ);    // 1024 f4
    int t = threadIdx.x, wave = t >> 6;
    f4 vals[4];
    float m = -1e30f;
    #pragma unroll
    for (int k = 0; k < 4; ++k) {
        vals[k] = row4[t + k * 256];
        m = fmaxf(m, fmaxf(fmaxf(vals[k].x, vals[k].y),
                           fmaxf(vals[k].z, vals[k].w)));
    }
    #pragma unroll
    for (int s = 32; s > 0; s >>= 1) m = fmaxf(m, __shfl_xor(m, s, 64));
    __shared__ float red_max[4];
    if (lane == 0) red_max[wave] = m;
    __syncthreads();
    m = fmaxf(fmaxf(red_max[0], red_max[1]), fmaxf(red_max[2], red_max[3]));

    float sum = 0.f;
    #pragma unroll
    for (int k = 0; k < 4; ++k) {
        vals[k].x = __expf(vals[k].x - m); vals[k].y = __expf(vals[k].y - m);
        vals[k].z = __expf(vals[k].z - m); vals[k].w = __expf(vals[k].w - m);
        sum += vals[k].x + vals[k].y + vals[k].z + vals[k].w;
    }
    #pragma unroll
    for (int s = 32; s > 0; s >>= 1) sum += __shfl_xor(sum, s, 64);
    __shared__ float red_sum[4];
    if (lane == 0) red_sum[wave] = sum;
    __syncthreads();
    sum = red_sum[0] + red_sum[1] + red_sum[2] + red_sum[3];

    float inv = 1.f / sum;
    #pragma unroll
    for (int k = 0; k < 4; ++k) {
        vals[k].x *= inv; vals[k].y *= inv; vals[k].z *= inv; vals[k].w *= inv;
        row4[t + k * 256] = vals[k];
    }
}

extern "C" void kernel_launch(void* const* d_in, const int* in_sizes, int n_in,
                              void* d_out, int out_size, void* d_ws, size_t ws_size,
                              hipStream_t stream) {
    const float* hidden = (const float*)d_in[0];   // [1,B,H]
    const float* enc    = (const float*)d_in[1];   // [B,S,H]
    const float* W      = (const float*)d_in[2];   // [H,H] row-major [o][h]
    // d_in[3] = b_attn: constant per-row shift inside softmax -> cancels; unused.
    float* out = (float*)d_out;                    // [B,1,S] == B*S floats
    float* v   = (float*)d_ws;                     // B*H floats = 64 KB
    int* counters = (int*)((char*)d_ws + BATCH * HID * sizeof(float));

    compute_v_kernel<<<dim3(BATCH, 2), 256, 0, stream>>>(hidden, W, v, counters);
    scores_softmax_kernel<<<(BATCH * SEQ) / 64, 256, 0, stream>>>(enc, v, out, counters);
}

// Round 6
// 54.645 us; speedup vs baseline: 7.4848x; 7.4848x over previous
//
#include <hip/hip_runtime.h>

#define BATCH 32
#define SEQ   4096
#define HID   512

typedef float f4 __attribute__((ext_vector_type(4)));

// v[b,h] = sum_o hidden[b,o] * W[o,h]   (b_attn cancels in softmax)
// grid (32, 2): block = (batch b, 256-wide h-half); o split across 4 waves,
// W read as float4 (1 KB per wave-instruction, coalesced).
__global__ void __launch_bounds__(256) compute_v_kernel(
        const float* __restrict__ hidden,
        const float* __restrict__ W,
        float* __restrict__ v) {
    int b    = blockIdx.x;
    int lane = threadIdx.x & 63;
    int wq   = threadIdx.x >> 6;               // o-quarter 0..3
    int h4   = blockIdx.y * 64 + lane;         // float4 column index 0..127

    __shared__ float sh[HID];
    for (int i = threadIdx.x; i < HID; i += 256) sh[i] = hidden[b * HID + i];
    __syncthreads();

    const f4* W4 = (const f4*)W;               // row o = 128 float4
    f4 acc = {0.f, 0.f, 0.f, 0.f};
    int o0 = wq * 128;
    #pragma unroll 8
    for (int o = o0; o < o0 + 128; ++o) {
        float s = sh[o];                       // broadcast (free)
        f4 w = W4[o * 128 + h4];               // 64 lanes x 16B contiguous
        acc.x = fmaf(s, w.x, acc.x);
        acc.y = fmaf(s, w.y, acc.y);
        acc.z = fmaf(s, w.z, acc.z);
        acc.w = fmaf(s, w.w, acc.w);
    }

    __shared__ f4 red[4][64];
    red[wq][lane] = acc;
    __syncthreads();
    if (wq == 0) {
        f4 r = red[0][lane];
        f4 a = red[1][lane], c = red[2][lane], d = red[3][lane];
        r.x += a.x + c.x + d.x;  r.y += a.y + c.y + d.y;
        r.z += a.z + c.z + d.z;  r.w += a.w + c.w + d.w;
        ((f4*)(v + (long long)b * HID))[h4] = r;
    }
}

// scores[b,s] = dot(enc[b,s,:], v[b,:])
// wave = 16 consecutive rows of ONE batch; v hoisted to registers;
// 4-row unroll (8 coalesced float4 loads in flight); packed dual-row reduce.
__global__ void __launch_bounds__(256) scores_kernel(
        const float* __restrict__ enc,
        const float* __restrict__ v,
        float* __restrict__ scores) {
    int wid  = blockIdx.x * 4 + (threadIdx.x >> 6);   // 0..8191
    int lane = threadIdx.x & 63;
    int b    = wid >> 8;                              // 256 waves per batch
    long long row0 = (long long)wid * 16;

    const f4* v4 = (const f4*)(v + (long long)b * HID);
    f4 v0 = v4[lane];                                 // cached, loaded once
    f4 v1 = v4[lane + 64];

    for (int r = 0; r < 16; r += 4) {
        const f4* e0 = (const f4*)(enc + (row0 + r)     * HID);
        const f4* e1 = (const f4*)(enc + (row0 + r + 1) * HID);
        const f4* e2 = (const f4*)(enc + (row0 + r + 2) * HID);
        const f4* e3 = (const f4*)(enc + (row0 + r + 3) * HID);
        f4 a0 = e0[lane], a1 = e0[lane + 64];
        f4 b0 = e1[lane], b1 = e1[lane + 64];
        f4 c0 = e2[lane], c1 = e2[lane + 64];
        f4 d0 = e3[lane], d1 = e3[lane + 64];

        float accA = a0.x*v0.x + a0.y*v0.y + a0.z*v0.z + a0.w*v0.w
                   + a1.x*v1.x + a1.y*v1.y + a1.z*v1.z + a1.w*v1.w;
        float accB = b0.x*v0.x + b0.y*v0.y + b0.z*v0.z + b0.w*v0.w
                   + b1.x*v1.x + b1.y*v1.y + b1.z*v1.z + b1.w*v1.w;
        float accC = c0.x*v0.x + c0.y*v0.y + c0.z*v0.z + c0.w*v0.w
                   + c1.x*v1.x + c1.y*v1.y + c1.z*v1.z + c1.w*v1.w;
        float accD = d0.x*v0.x + d0.y*v0.y + d0.z*v0.z + d0.w*v0.w
                   + d1.x*v1.x + d1.y*v1.y + d1.z*v1.z + d1.w*v1.w;

        // pack rows (A,B) into (lower,upper) 32-lane halves with one xor-32
        // swap, then one 5-level fold reduces both rows. Same for (C,D).
        float zab = (lane < 32) ? accA : accB;
        zab += __shfl_xor((lane < 32) ? accB : accA, 32, 64);
        float zcd = (lane < 32) ? accC : accD;
        zcd += __shfl_xor((lane < 32) ? accD : accC, 32, 64);
        #pragma unroll
        for (int m = 16; m > 0; m >>= 1) {
            zab += __shfl_xor(zab, m, 64);
            zcd += __shfl_xor(zcd, m, 64);
        }
        if (lane == 0)  { scores[row0 + r]     = zab; scores[row0 + r + 2] = zcd; }
        if (lane == 32) { scores[row0 + r + 1] = zab; scores[row0 + r + 3] = zcd; }
    }
}

// in-place softmax over 4096 scores per batch row; 1024 threads, float4 I/O
__global__ void __launch_bounds__(1024) softmax_kernel(float* __restrict__ data) {
    int b = blockIdx.x;
    f4* row4 = (f4*)(data + (long long)b * SEQ);
    int t = threadIdx.x, wave = t >> 6, lane = t & 63;

    f4 vv = row4[t];                                   // coalesced, 16 KB/block
    float m = fmaxf(fmaxf(vv.x, vv.y), fmaxf(vv.z, vv.w));
    #pragma unroll
    for (int s = 32; s > 0; s >>= 1) m = fmaxf(m, __shfl_xor(m, s, 64));
    __shared__ float red_max[16];
    if (lane == 0) red_max[wave] = m;
    __syncthreads();
    m = red_max[0];
    #pragma unroll
    for (int i = 1; i < 16; ++i) m = fmaxf(m, red_max[i]);

    vv.x = __expf(vv.x - m); vv.y = __expf(vv.y - m);
    vv.z = __expf(vv.z - m); vv.w = __expf(vv.w - m);
    float sum = vv.x + vv.y + vv.z + vv.w;
    #pragma unroll
    for (int s = 32; s > 0; s >>= 1) sum += __shfl_xor(sum, s, 64);
    __shared__ float red_sum[16];
    if (lane == 0) red_sum[wave] = sum;
    __syncthreads();
    sum = 0.f;
    #pragma unroll
    for (int i = 0; i < 16; ++i) sum += red_sum[i];

    float inv = 1.f / sum;
    vv.x *= inv; vv.y *= inv; vv.z *= inv; vv.w *= inv;
    row4[t] = vv;
}

extern "C" void kernel_launch(void* const* d_in, const int* in_sizes, int n_in,
                              void* d_out, int out_size, void* d_ws, size_t ws_size,
                              hipStream_t stream) {
    const float* hidden = (const float*)d_in[0];   // [1,B,H]
    const float* enc    = (const float*)d_in[1];   // [B,S,H]
    const float* W      = (const float*)d_in[2];   // [H,H] row-major [o][h]
    // d_in[3] = b_attn: constant per-row shift inside softmax -> cancels; unused.
    float* out = (float*)d_out;                    // [B,1,S] == B*S floats
    float* v   = (float*)d_ws;                     // B*H floats = 64 KB scratch

    compute_v_kernel<<<dim3(BATCH, 2), 256, 0, stream>>>(hidden, W, v);
    scores_kernel<<<(BATCH * SEQ) / (16 * 4), 256, 0, stream>>>(enc, v, out);
    softmax_kernel<<<BATCH, 1024, 0, stream>>>(out);
}